// Round 8
// baseline (244.990 us; speedup 1.0000x reference)
//
#include <hip/hip_runtime.h>
#include <math.h>

// CrowdDet RetinaNet loss constants
#define POS_T 0.5f
#define NEG_T 0.4f
#define F_ALPHA 0.25f
#define SL1_BETA 0.1f
#define SENT 3.0e8f

// d_ws layout:
//   [0,24)      : 3 doubles (loss_cls, loss_reg, num_pos)
//   [512, +XB)  : X — SGPR-chunk SoA tiles. Per batch: NC chunks x 40 floats:
//                 chunk c = {G0[8], G1[8], G2P[8], G3P[8], AREA[8]}
//                 (G2P/G3P carry the pre-added +1; sentinels never win argmax)
//   [Yoff, ...) : Y — epilogue records, stride 8 floats per gt:
//                 {g0, g1, g2, g3, cls, 0, 0, 0}
#define WS_X_BYTE_OFF 512

typedef __attribute__((ext_vector_type(8))) int i8x;

__device__ __forceinline__ float smooth_l1(float d) {
    d = fabsf(d);
    return d < SL1_BETA ? 0.5f * d * d / SL1_BETA : d - SL1_BETA;
}

__global__ void prep_gt_kernel(const float* __restrict__ gt,
                               const float* __restrict__ im_info,
                               float* __restrict__ X, float* __restrict__ Y,
                               double* __restrict__ ws,
                               int G, int Gp, int NC, int B) {
#pragma clang fp contract(off)
    const int i = blockIdx.x * 256 + threadIdx.x;
    if (i < 3) ws[i] = 0.0;
    const int total = B * Gp;
    if (i >= total) return;
    const int b = i / Gp, j = i - b * Gp;
    const int nv = (int)im_info[b * 6 + 5];

    float g0, g1, g2, g3, cls, area;
    if (j < nv) {
        const float* s = gt + ((size_t)b * G + j) * 5;
        g0 = s[0]; g1 = s[1]; g2 = s[2]; g3 = s[3]; cls = s[4];
        area = (g2 - g0 + 1.f) * (g3 - g1 + 1.f);   // exact ref op order
    } else {
        // Sentinel far-away box: inter = 0 with any real anchor; once a real
        // gt is in (bi >= 0), 0*bS > bi*S never holds -> can't win argmax.
        g0 = SENT; g1 = SENT; g2 = SENT + 1.f; g3 = SENT + 1.f;
        cls = 0.f; area = 4.f;
    }

    float* xc = X + (size_t)b * NC * 40 + (size_t)(j >> 3) * 40;
    const int l = j & 7;
    xc[0 * 8 + l] = g0;
    xc[1 * 8 + l] = g1;
    xc[2 * 8 + l] = g2 + 1.f;    // pre-added +1 for iw/ih
    xc[3 * 8 + l] = g3 + 1.f;
    xc[4 * 8 + l] = area;

    float* y = Y + ((size_t)b * Gp + j) * 8;
    reinterpret_cast<float4*>(y)[0] = make_float4(g0, g1, g2, g3);
    y[4] = cls;
}

// Block = 4 waves over the SAME 64 anchors; wave w scans GT-chunk quarter w.
// Candidates merged in LDS in quarter order (first-max preserved), wave 0
// runs the epilogue. 4x the wave count of 1-anchor/thread -> saturated TLP.
__global__ __launch_bounds__(256) void retina_loss_kernel(
    const float* __restrict__ pred_cls,   // [B,A,1]
    const float* __restrict__ pred_reg,   // [B,A,4]
    const float* __restrict__ anchors,    // [A,4]
    const float* __restrict__ im_info,    // [B,6]
    const float* __restrict__ X,          // SoA chunks
    const float* __restrict__ Y,          // epilogue records
    int A, int NC, int Gp,
    double* __restrict__ ws)
{
#pragma clang fp contract(off)
    __shared__ float4 sP[256];            // [wave][lane] candidate {bi,bS,arg,-}

    const int b = blockIdx.y;
    const int lane = threadIdx.x & 63;
    const int wid = __builtin_amdgcn_readfirstlane(threadIdx.x >> 6); // uniform
    const int a_raw = blockIdx.x * 64 + lane;
    const bool live = a_raw < A;
    const int a = min(a_raw, A - 1);

    const int nvalid = __builtin_amdgcn_readfirstlane((int)im_info[b * 6 + 5]);
    const int nch = (nvalid + 7) >> 3;
    // Chunk quarter for this wave (SALU): {q+1}x r then {q}x (4-r)
    const int q = nch >> 2, r = nch & 3;
    const int cstart = wid * q + min(wid, r);
    const int cend = cstart + q + (wid < r ? 1 : 0);

    const float* __restrict__ Xb = X + (size_t)b * NC * 40;
    const float* __restrict__ Yb = Y + (size_t)b * Gp * 8;

    const float4 anc = *reinterpret_cast<const float4*>(anchors + 4 * (size_t)a);
    const float a0 = anc.x, a1 = anc.y;
    const float aw = anc.z - anc.x + 1.f;
    const float ah = anc.w - anc.y + 1.f;
    const float area_a = aw * ah;
    const float a2p = anc.z + 1.f;        // +1 pre-added (monotone rounding
    const float a3p = anc.w + 1.f;        //  commutes with min bit-exactly)

    // Division-free IoU argmax: iou = inter/(S-inter) monotone in inter/S =>
    // iou_i > iou_j  <=>  inter_i*S_j > inter_j*S_i (S>0). Init (-1,1):
    // first gt always wins; strict > == first-max (jnp.argmax tie-break).
    float bi = -1.f, bS = 1.f;
    int arg = 0;

    for (int c = cstart; c < cend; ++c) {
        const float* cp = Xb + (size_t)c * 40;
        i8x r0, r1, r2, r3, r4;
        asm volatile(
            "s_load_dwordx8 %0, %5, 0x0\n\t"
            "s_load_dwordx8 %1, %5, 0x20\n\t"
            "s_load_dwordx8 %2, %5, 0x40\n\t"
            "s_load_dwordx8 %3, %5, 0x60\n\t"
            "s_load_dwordx8 %4, %5, 0x80\n\t"
            "s_waitcnt lgkmcnt(0)"
            : "=s"(r0), "=s"(r1), "=s"(r2), "=s"(r3), "=s"(r4)
            : "s"(cp));
        const int cb = c << 3;
        #pragma unroll
        for (int j = 0; j < 8; ++j) {
            const float g0  = __int_as_float(r0[j]);
            const float g1  = __int_as_float(r1[j]);
            const float g2p = __int_as_float(r2[j]);
            const float g3p = __int_as_float(r3[j]);
            const float sg  = __int_as_float(r4[j]);
            const float iw = fminf(a2p, g2p) - fmaxf(a0, g0);
            const float ih = fminf(a3p, g3p) - fmaxf(a1, g1);
            const float inter = fmaxf(iw, 0.f) * fmaxf(ih, 0.f);
            const float S = area_a + sg;
            const bool upd = inter * bS > bi * S;
            bi  = upd ? inter    : bi;
            bS  = upd ? S        : bS;
            arg = upd ? (cb + j) : arg;
        }
    }

    // Publish candidate; float4 stride (16 B) -> conflict-free b128.
    sP[wid * 64 + lane] = make_float4(bi, bS, __int_as_float(arg), 0.f);
    __syncthreads();

    float lc = 0.f, lr = 0.f;
    int fg = 0;

    if (wid == 0) {
        // Fold quarters in index order: replace only on strictly greater.
        #pragma unroll
        for (int w = 1; w < 4; ++w) {
            const float4 cnd = sP[w * 64 + lane];
            const float biw = cnd.x, bSw = cnd.y;
            const bool upd = biw * bS > bi * bSw;
            bi  = upd ? biw : bi;
            bS  = upd ? bSw : bS;
            arg = upd ? __float_as_int(cnd.z) : arg;
        }

        if (live) {
            // ONE division, exact ref expression: inter/((area_a+area_g)-inter)
            const float max_ov = bi / (bS - bi);

            float label = 0.f;
            bool valid = true;
            if (max_ov >= POS_T) {
                label = Yb[(size_t)arg * 8 + 4];
            } else if (max_ov >= NEG_T) {
                valid = false;                 // ignore band
            }
            fg = (label > 0.f) ? 1 : 0;

            if (valid) {
                const float x = pred_cls[(size_t)b * A + a];
                const float p = 1.f / (1.f + expf(-x));
                const float l1p = log1pf(expf(-fabsf(x)));
                const float log_p  = fminf(x, 0.f) - l1p;    // log_sigmoid(x)
                const float log_np = fminf(-x, 0.f) - l1p;   // log_sigmoid(-x)
                const float pos = (label == 1.f) ? 1.f : 0.f;
                const float omp = 1.f - p;
                lc = -(F_ALPHA * pos * (omp * omp) * log_p
                       + (1.f - F_ALPHA) * (1.f - pos) * (p * p) * log_np);
            }

            if (fg) {
                const float4 gb = *reinterpret_cast<const float4*>(Yb + (size_t)arg * 8);
                const float gw = gb.z - gb.x + 1.f;
                const float gh = gb.w - gb.y + 1.f;
                const float gx = gb.x + 0.5f * gw;
                const float gy = gb.y + 0.5f * gh;
                const float axc = a0 + 0.5f * aw;
                const float ayc = a1 + 0.5f * ah;
                const float t0 = (gx - axc) / aw;
                const float t1 = (gy - ayc) / ah;
                const float t2 = logf(gw / aw);
                const float t3 = logf(gh / ah);
                const float4 rr = *reinterpret_cast<const float4*>(
                    pred_reg + 4 * ((size_t)b * A + a));
                lr = smooth_l1(rr.x - t0) + smooth_l1(rr.y - t1)
                   + smooth_l1(rr.z - t2) + smooth_l1(rr.w - t3);
            }
        }

        // wave64 reduction (wave 0 only) + one atomic triple per block
        for (int off = 32; off > 0; off >>= 1) {
            lc += __shfl_down(lc, off);
            lr += __shfl_down(lr, off);
            fg += __shfl_down(fg, off);
        }
        if (lane == 0) {
            __hip_atomic_fetch_add(&ws[0], (double)lc, __ATOMIC_RELAXED, __HIP_MEMORY_SCOPE_AGENT);
            __hip_atomic_fetch_add(&ws[1], (double)lr, __ATOMIC_RELAXED, __HIP_MEMORY_SCOPE_AGENT);
            __hip_atomic_fetch_add(&ws[2], (double)fg, __ATOMIC_RELAXED, __HIP_MEMORY_SCOPE_AGENT);
        }
    }
}

__global__ void finalize_kernel(const double* __restrict__ ws, float* __restrict__ out) {
    if (threadIdx.x == 0 && blockIdx.x == 0) {
        const double npos = ws[2] < 1.0 ? 1.0 : ws[2];
        const double norm = 0.9 * 100.0 + 0.1 * npos;
        out[0] = (float)(ws[0] / norm);
        out[1] = (float)(ws[1] / norm);
    }
}

extern "C" void kernel_launch(void* const* d_in, const int* in_sizes, int n_in,
                              void* d_out, int out_size, void* d_ws, size_t ws_size,
                              hipStream_t stream) {
    const float* pred_cls = (const float*)d_in[0];
    const float* pred_reg = (const float*)d_in[1];
    const float* anchors  = (const float*)d_in[2];
    const float* gt_boxes = (const float*)d_in[3];
    const float* im_info  = (const float*)d_in[4];

    const int A = in_sizes[2] / 4;
    const int B = in_sizes[4] / 6;
    const int G = in_sizes[3] / (B * 5);
    const int NC = (G + 7) / 8;                  // 8-gt chunks
    const int Gp = NC * 8;                       // sentinel-padded gt count

    double* ws = (double*)d_ws;
    float* X = (float*)((char*)d_ws + WS_X_BYTE_OFF);
    const size_t xbytes = (size_t)B * NC * 40 * sizeof(float);
    float* Y = (float*)((char*)d_ws + WS_X_BYTE_OFF + ((xbytes + 255) & ~(size_t)255));

    const int total_slots = B * Gp;
    prep_gt_kernel<<<(total_slots + 255) / 256, 256, 0, stream>>>(
        gt_boxes, im_info, X, Y, ws, G, Gp, NC, B);

    dim3 grid((A + 63) / 64, B);                 // 64 anchors per block
    retina_loss_kernel<<<grid, 256, 0, stream>>>(
        pred_cls, pred_reg, anchors, im_info, X, Y, A, NC, Gp, ws);
    finalize_kernel<<<1, 1, 0, stream>>>(ws, (float*)d_out);
}

// Round 9
// 101.880 us; speedup vs baseline: 2.4047x; 2.4047x over previous
//
#include <hip/hip_runtime.h>
#include <math.h>

// CrowdDet RetinaNet loss constants
#define POS_T 0.5f
#define NEG_T 0.4f
#define F_ALPHA 0.25f
#define SL1_BETA 0.1f
#define SENT 3.0e8f

// d_ws layout:
//   [0, 512)    : 3 doubles at indices 0, 16, 32 (loss_cls, loss_reg, num_pos)
//                 -- padded to separate cache lines (atomic ping-pong insurance)
//   [512, +XB)  : X4 — per batch (Gp+64) float4 records {g0, g1, g2+1, g3+1}
//                 (slot j >= nvalid = sentinel far box; extra 64 = prefetch pad)
//   [Aoff, ...) : AREA — per batch (Gp+64) floats (area_g; sentinel = 4)
//   [Yoff, ...) : Y — epilogue records, stride 8 floats per gt:
//                 {g0, g1, g2, g3, cls, 0, 0, 0}
#define WS_X_BYTE_OFF 512

__device__ __forceinline__ float smooth_l1(float d) {
    d = fabsf(d);
    return d < SL1_BETA ? 0.5f * d * d / SL1_BETA : d - SL1_BETA;
}

// Broadcast lane j's value to all lanes (VALU v_readlane, SGPR dst, imm lane).
__device__ __forceinline__ float rl(float x, int j) {
    return __int_as_float(__builtin_amdgcn_readlane(__float_as_int(x), j));
}

__global__ void prep_gt_kernel(const float* __restrict__ gt,
                               const float* __restrict__ im_info,
                               float4* __restrict__ X4, float* __restrict__ AREA,
                               float* __restrict__ Y, double* __restrict__ ws,
                               int G, int Gslots, int B) {
#pragma clang fp contract(off)
    const int i = blockIdx.x * 256 + threadIdx.x;
    if (i < 34) ws[i] = 0.0;
    const int total = B * Gslots;
    if (i >= total) return;
    const int b = i / Gslots, j = i - b * Gslots;
    const int nv = (int)im_info[b * 6 + 5];

    float g0, g1, g2, g3, cls, area;
    if (j < nv) {
        const float* s = gt + ((size_t)b * G + j) * 5;
        g0 = s[0]; g1 = s[1]; g2 = s[2]; g3 = s[3]; cls = s[4];
        area = (g2 - g0 + 1.f) * (g3 - g1 + 1.f);   // exact ref op order
    } else {
        // Sentinel far-away box: inter = 0 with any real anchor; once a real
        // gt is in (bi >= 0), 0*bS > bi*S never holds -> can't win argmax.
        g0 = SENT; g1 = SENT; g2 = SENT + 1.f; g3 = SENT + 1.f;
        cls = 0.f; area = 4.f;
    }

    X4[i] = make_float4(g0, g1, g2 + 1.f, g3 + 1.f);  // pre-added +1 for iw/ih
    AREA[i] = area;

    float* y = Y + (size_t)i * 8;
    reinterpret_cast<float4*>(y)[0] = make_float4(g0, g1, g2, g3);
    y[4] = cls;
}

// 1 anchor/thread. GT records enter the wave ONCE via coalesced per-lane
// loads (64 gts/round, reg-double-buffered); in-loop distribution is pure
// v_readlane broadcast -> zero memory ops on the critical path.
__global__ __launch_bounds__(256) void retina_loss_kernel(
    const float* __restrict__ pred_cls,   // [B,A,1]
    const float* __restrict__ pred_reg,   // [B,A,4]
    const float* __restrict__ anchors,    // [A,4]
    const float* __restrict__ im_info,    // [B,6]
    const float4* __restrict__ X4,        // per-lane GT records
    const float* __restrict__ AREA,
    const float* __restrict__ Y,          // epilogue records
    int A, int Gslots,
    double* __restrict__ ws)
{
#pragma clang fp contract(off)
    const int b = blockIdx.y;
    const int lane = threadIdx.x & 63;
    const int a_raw = blockIdx.x * 256 + threadIdx.x;
    const bool live = a_raw < A;
    const int a = min(a_raw, A - 1);      // clamp: uniform control flow
    const int nvalid = __builtin_amdgcn_readfirstlane((int)im_info[b * 6 + 5]);
    const int nrounds = (nvalid + 63) >> 6;   // sentinels cover the tail
    const float4* __restrict__ X4b = X4 + (size_t)b * Gslots;
    const float* __restrict__ Ab = AREA + (size_t)b * Gslots;
    const float* __restrict__ Yb = Y + (size_t)b * Gslots * 8;

    const float4 anc = *reinterpret_cast<const float4*>(anchors + 4 * (size_t)a);
    const float a0 = anc.x, a1 = anc.y;
    const float aw = anc.z - anc.x + 1.f;
    const float ah = anc.w - anc.y + 1.f;
    const float area_a = aw * ah;
    const float a2p = anc.z + 1.f;        // +1 pre-added (monotone rounding
    const float a3p = anc.w + 1.f;        //  commutes with min bit-exactly)

    // Division-free IoU argmax: iou = inter/(S-inter) monotone in inter/S =>
    // iou_i > iou_j  <=>  inter_i*S_j > inter_j*S_i (S>0). Init (-1,1):
    // first gt always wins; strict > == first-max (jnp.argmax tie-break).
    // Scan order identical to the sequential reference loop.
    float bi = -1.f, bS = 1.f;
    int arg = 0;

    // Round 0 data (per-lane, coalesced). Prefetch pad makes r+1 always valid.
    float4 q = X4b[lane];
    float ar = Ab[lane];

    for (int r = 0; r < nrounds; ++r) {
        const float4 nq = X4b[(r + 1) * 64 + lane];   // prefetch next round
        const float nar = Ab[(r + 1) * 64 + lane];
        const int rbase = r << 6;
        #pragma unroll
        for (int j = 0; j < 64; ++j) {
            const float g0  = rl(q.x, j);   // v_readlane -> SGPR
            const float g1  = rl(q.y, j);
            const float g2p = rl(q.z, j);
            const float g3p = rl(q.w, j);
            const float sg  = rl(ar, j);
            const float iw = fminf(a2p, g2p) - fmaxf(a0, g0);
            const float ih = fminf(a3p, g3p) - fmaxf(a1, g1);
            const float inter = fmaxf(iw, 0.f) * fmaxf(ih, 0.f);
            const float S = area_a + sg;
            const bool upd = inter * bS > bi * S;
            bi  = upd ? inter : bi;
            bS  = upd ? S     : bS;
            arg = upd ? (rbase + j) : arg;
        }
        q = nq; ar = nar;
    }

    float lc = 0.f, lr = 0.f;
    int fg = 0;

    if (live) {
        // ONE division, exact ref expression: inter/((area_a+area_g)-inter)
        const float max_ov = bi / (bS - bi);

        float label = 0.f;
        bool valid = true;
        if (max_ov >= POS_T) {
            label = Yb[(size_t)arg * 8 + 4];
        } else if (max_ov >= NEG_T) {
            valid = false;                 // ignore band
        }
        fg = (label > 0.f) ? 1 : 0;

        if (valid) {
            const float x = pred_cls[(size_t)b * A + a];
            const float p = 1.f / (1.f + expf(-x));
            const float l1p = log1pf(expf(-fabsf(x)));
            const float log_p  = fminf(x, 0.f) - l1p;    // log_sigmoid(x)
            const float log_np = fminf(-x, 0.f) - l1p;   // log_sigmoid(-x)
            const float pos = (label == 1.f) ? 1.f : 0.f;
            const float omp = 1.f - p;
            lc = -(F_ALPHA * pos * (omp * omp) * log_p
                   + (1.f - F_ALPHA) * (1.f - pos) * (p * p) * log_np);
        }

        if (fg) {
            const float4 gb = *reinterpret_cast<const float4*>(Yb + (size_t)arg * 8);
            const float gw = gb.z - gb.x + 1.f;
            const float gh = gb.w - gb.y + 1.f;
            const float gx = gb.x + 0.5f * gw;
            const float gy = gb.y + 0.5f * gh;
            const float axc = a0 + 0.5f * aw;
            const float ayc = a1 + 0.5f * ah;
            const float t0 = (gx - axc) / aw;
            const float t1 = (gy - ayc) / ah;
            const float t2 = logf(gw / aw);
            const float t3 = logf(gh / ah);
            const float4 rr = *reinterpret_cast<const float4*>(
                pred_reg + 4 * ((size_t)b * A + a));
            lr = smooth_l1(rr.x - t0) + smooth_l1(rr.y - t1)
               + smooth_l1(rr.z - t2) + smooth_l1(rr.w - t3);
        }
    }

    // wave64 reduction
    for (int off = 32; off > 0; off >>= 1) {
        lc += __shfl_down(lc, off);
        lr += __shfl_down(lr, off);
        fg += __shfl_down(fg, off);
    }

    __shared__ float s_lc[4], s_lr[4];
    __shared__ int s_np[4];
    const int wid = threadIdx.x >> 6;
    if (lane == 0) { s_lc[wid] = lc; s_lr[wid] = lr; s_np[wid] = fg; }
    __syncthreads();
    if (threadIdx.x == 0) {
        const float tlc = s_lc[0] + s_lc[1] + s_lc[2] + s_lc[3];
        const float tlr = s_lr[0] + s_lr[1] + s_lr[2] + s_lr[3];
        const int   tnp = s_np[0] + s_np[1] + s_np[2] + s_np[3];
        __hip_atomic_fetch_add(&ws[0],  (double)tlc, __ATOMIC_RELAXED, __HIP_MEMORY_SCOPE_AGENT);
        __hip_atomic_fetch_add(&ws[16], (double)tlr, __ATOMIC_RELAXED, __HIP_MEMORY_SCOPE_AGENT);
        __hip_atomic_fetch_add(&ws[32], (double)tnp, __ATOMIC_RELAXED, __HIP_MEMORY_SCOPE_AGENT);
    }
}

__global__ void finalize_kernel(const double* __restrict__ ws, float* __restrict__ out) {
    if (threadIdx.x == 0 && blockIdx.x == 0) {
        const double npos = ws[32] < 1.0 ? 1.0 : ws[32];
        const double norm = 0.9 * 100.0 + 0.1 * npos;
        out[0] = (float)(ws[0] / norm);
        out[1] = (float)(ws[16] / norm);
    }
}

extern "C" void kernel_launch(void* const* d_in, const int* in_sizes, int n_in,
                              void* d_out, int out_size, void* d_ws, size_t ws_size,
                              hipStream_t stream) {
    const float* pred_cls = (const float*)d_in[0];
    const float* pred_reg = (const float*)d_in[1];
    const float* anchors  = (const float*)d_in[2];
    const float* gt_boxes = (const float*)d_in[3];
    const float* im_info  = (const float*)d_in[4];

    const int A = in_sizes[2] / 4;
    const int B = in_sizes[4] / 6;
    const int G = in_sizes[3] / (B * 5);
    const int Gp = (G + 63) & ~63;               // pad to 64-gt rounds
    const int Gslots = Gp + 64;                  // + prefetch pad round

    double* ws = (double*)d_ws;
    char* base = (char*)d_ws + WS_X_BYTE_OFF;
    float4* X4 = (float4*)base;
    const size_t x4b = (size_t)B * Gslots * sizeof(float4);
    float* AREA = (float*)(base + ((x4b + 255) & ~(size_t)255));
    const size_t arb = (size_t)B * Gslots * sizeof(float);
    float* Y = (float*)(base + ((x4b + 255) & ~(size_t)255) + ((arb + 255) & ~(size_t)255));

    const int total_slots = B * Gslots;
    prep_gt_kernel<<<(total_slots + 255) / 256, 256, 0, stream>>>(
        gt_boxes, im_info, X4, AREA, Y, ws, G, Gslots, B);

    dim3 grid((A + 255) / 256, B);
    retina_loss_kernel<<<grid, 256, 0, stream>>>(
        pred_cls, pred_reg, anchors, im_info, X4, AREA, Y, A, Gslots, ws);
    finalize_kernel<<<1, 1, 0, stream>>>(ws, (float*)d_out);
}